// Round 2
// baseline (1163.364 us; speedup 1.0000x reference)
//
#include <hip/hip_runtime.h>
#include <hip/hip_bf16.h>

// WindowAttention fused kernel for MI355X (gfx950).
// 4096 windows, N=64 tokens, DIM=256, NH=1. fp32 I/O, bf16 MFMA compute.
// One block per window, 512 threads (8 waves). All GEMMs via
// v_mfma_f32_16x16x32_bf16. Weights repacked (fp32->bf16, B-frag order) each
// launch; bias table (64 theta values x 64x64, fp32) precomputed each launch.

typedef __attribute__((ext_vector_type(8))) short short8;
typedef __attribute__((ext_vector_type(4))) float f32x4;

// fp32 -> bf16 bits, sanitizing NaN/Inf (IEEE maxNum: fmaxf(NaN,a)=a) so a
// dtype misread produces large-finite output (diagnostic), never NaN.
__device__ __forceinline__ unsigned short f2bf(float f) {
    f = fmaxf(f, -3.0e38f);
    f = fminf(f, 3.0e38f);
    __hip_bfloat16 h = __float2bfloat16(f);
    return *reinterpret_cast<unsigned short*>(&h);
}
__device__ __forceinline__ float sane(float f) {
    f = fmaxf(f, -1.0e10f);
    return fminf(f, 1.0e10f);
}

// ---------------------------------------------------------------- prep ----
// Repack qkv_w (256x768 fp32) and proj_w (256x256 fp32) into bf16 MFMA
// B-fragment order: idx = ((ntile*8 + ktile)*64 + lane)*8 + j
//   <->  W[k = 32*ktile + 8*(lane>>4) + j][n = 16*ntile + (lane&15)]
__global__ void prep_repack(const float* __restrict__ qkv_w,
                            const float* __restrict__ proj_w,
                            unsigned short* __restrict__ wq_pack,
                            unsigned short* __restrict__ wp_pack) {
    int t = blockIdx.x * blockDim.x + threadIdx.x;
    if (t < 24576) {             // 48 ntiles * 8 ktiles * 64 lanes
        int lane = t & 63, kt = (t >> 6) & 7, nt = t >> 9;
        int k0 = kt * 32 + (lane >> 4) * 8;
        int n  = nt * 16 + (lane & 15);
        unsigned short* dst = wq_pack + t * 8;
        for (int j = 0; j < 8; ++j) dst[j] = f2bf(qkv_w[(k0 + j) * 768 + n]);
    } else if (t < 32768) {      // 16 ntiles * 8 ktiles * 64 lanes
        int t2 = t - 24576;
        int lane = t2 & 63, kt = (t2 >> 6) & 7, nt = t2 >> 9;
        int k0 = kt * 32 + (lane >> 4) * 8;
        int n  = nt * 16 + (lane & 15);
        unsigned short* dst = wp_pack + t2 * 8;
        for (int j = 0; j < 8; ++j) dst[j] = f2bf(proj_w[(k0 + j) * 256 + n]);
    }
}

// btab[t][i][j] = A_phi[i][j] + A_th(theta_max[t])[i][j], fp32, 64 x 4096
__global__ void prep_bias(const float* __restrict__ theta_max,
                          const float* __restrict__ a_p,
                          const float* __restrict__ b_p,
                          const float* __restrict__ a_r,
                          const float* __restrict__ b_r,
                          float* __restrict__ btab) {
    int idx = blockIdx.x * blockDim.x + threadIdx.x;
    if (idx >= 64 * 4096) return;
    int t = idx >> 12, ij = idx & 4095, i = ij >> 6, j = ij & 63;
    int ri = (i >> 3) - (j >> 3);          // radius (y diff) in [-7,7]
    int az = (i & 7) - (j & 7);            // azimuth (x diff) in [-7,7]
    int azi = az < 0 ? az + 15 : az;       // torch negative wrap: mod 15
    int rii = ri < 0 ? ri + 15 : ri;
    float ang = (float)az * (6.28318530717958647692f / 64.0f);
    float aphi = a_p[azi] * cosf(ang) + b_p[azi] * sinf(ang);
    float rn = (float)ri * theta_max[t] * (1.0f / 64.0f);
    float ath = a_r[rii] * cosf(rn) + b_r[rii] * sinf(rn);
    btab[idx] = sane(aphi + ath);
}

// ---------------------------------------------------------------- main ----
// LDS layout (ushort elements):
//   kbuf 0      .. 16896   (64 x 264 row-major k, bf16)
//   qbuf 16896  .. 33792   (64 x 264 row-major q*scale; later ao)
//   vt   33792  .. 52224   (256 x 72, v transposed [dim][token])
//   xbuf 52224  .. 60928   (64 x 136 half-K x staging; later P 64 x 72)
//   red  byte 121856       (pmax[128] + psum[128] fp32)
// total 122880 bytes dynamic LDS -> 1 block/CU (LDS-bound).
#define LDS_BYTES 122880

__global__ __launch_bounds__(512, 1)
void wattn_main(const float* __restrict__ x,
                const float* __restrict__ qkv_b,
                const float* __restrict__ proj_b,
                const unsigned short* __restrict__ wq_pack,
                const unsigned short* __restrict__ wp_pack,
                const float* __restrict__ btab,
                float* __restrict__ out) {
    extern __shared__ char smem[];
    unsigned short* kbuf = (unsigned short*)smem;
    unsigned short* qbuf = kbuf + 16896;
    unsigned short* vt   = qbuf + 16896;
    unsigned short* xbuf = vt + 18432;
    float* pmaxs = (float*)(smem + 121856);
    float* psums = pmaxs + 128;

    const int tid = threadIdx.x;
    const int w = tid >> 6, lane = tid & 63;
    const int g = lane >> 4, c = lane & 15;
    const int b = blockIdx.x;
    const float* xb = x + (size_t)b * 64 * 256;

    // ======== GEMM1: qkv = x @ Wqkv (+b). wave w owns out cols 96w..96w+95.
    f32x4 acc[6][4];
    for (int nt = 0; nt < 6; ++nt)
        for (int mt = 0; mt < 4; ++mt)
            acc[nt][mt] = f32x4{0.f, 0.f, 0.f, 0.f};

    for (int h = 0; h < 2; ++h) {
        // stage x[:, 128h..128h+127] fp32 -> bf16 into xbuf (64 x 136)
        for (int ch = tid; ch < 2048; ch += 512) {
            int tok = ch >> 5, d4 = ch & 31;
            float4 v4 = *(const float4*)(xb + tok * 256 + h * 128 + d4 * 4);
            unsigned short* dst = xbuf + tok * 136 + d4 * 4;
            dst[0] = f2bf(v4.x); dst[1] = f2bf(v4.y);
            dst[2] = f2bf(v4.z); dst[3] = f2bf(v4.w);
        }
        __syncthreads();
        short8 af[4][4];
        for (int mt = 0; mt < 4; ++mt)
            for (int kt = 0; kt < 4; ++kt)
                af[mt][kt] = *(const short8*)(xbuf + (mt * 16 + c) * 136 + kt * 32 + g * 8);
        for (int nt = 0; nt < 6; ++nt) {
            int ntg = w * 6 + nt;
            short8 bfr[4];
            for (int kt = 0; kt < 4; ++kt)
                bfr[kt] = *(const short8*)(wq_pack + ((size_t)(ntg * 8 + h * 4 + kt) * 64 + lane) * 8);
            for (int mt = 0; mt < 4; ++mt)
                for (int kt = 0; kt < 4; ++kt)
                    acc[nt][mt] = __builtin_amdgcn_mfma_f32_16x16x32_bf16(
                        af[mt][kt], bfr[kt], acc[nt][mt], 0, 0, 0);
        }
        __syncthreads();
    }
    // epilogue: +bias, scatter to q (scaled), k, v^T
    for (int nt = 0; nt < 6; ++nt) {
        int ntg = w * 6 + nt;
        int col = ntg * 16 + c;
        float bias = sane(qkv_b[col]);
        for (int mt = 0; mt < 4; ++mt)
            for (int rr = 0; rr < 4; ++rr) {
                int row = mt * 16 + g * 4 + rr;
                float v = acc[nt][mt][rr] + bias;
                if (ntg < 16)       qbuf[row * 264 + col] = f2bf(v * 0.0625f);  // SCALE=1/16
                else if (ntg < 32)  kbuf[row * 264 + (col - 256)] = f2bf(v);
                else                vt[(col - 512) * 72 + row] = f2bf(v);
            }
    }
    __syncthreads();

    // ======== QK^T + bias + softmax. wave w: rows 16*(w>>1).., cols 32*(w&1)..
    const int mtq = w >> 1, nh = w & 1;
    f32x4 sacc[2];
    sacc[0] = f32x4{0.f, 0.f, 0.f, 0.f};
    sacc[1] = f32x4{0.f, 0.f, 0.f, 0.f};
    for (int kt = 0; kt < 8; ++kt) {
        short8 aq = *(const short8*)(qbuf + (mtq * 16 + c) * 264 + kt * 32 + g * 8);
        for (int n2 = 0; n2 < 2; ++n2) {
            short8 bk = *(const short8*)(kbuf + ((nh * 2 + n2) * 16 + c) * 264 + kt * 32 + g * 8);
            sacc[n2] = __builtin_amdgcn_mfma_f32_16x16x32_bf16(aq, bk, sacc[n2], 0, 0, 0);
        }
    }
    const float* bt = btab + (size_t)(b >> 6) * 4096;
    float mloc[4];
    for (int rr = 0; rr < 4; ++rr) {
        int row = mtq * 16 + g * 4 + rr;
        float s0 = sacc[0][rr] + bt[row * 64 + nh * 32 + c];
        float s1 = sacc[1][rr] + bt[row * 64 + nh * 32 + 16 + c];
        sacc[0][rr] = s0; sacc[1][rr] = s1;
        float mx = fmaxf(s0, s1);
        mx = fmaxf(mx, __shfl_xor(mx, 1, 16));
        mx = fmaxf(mx, __shfl_xor(mx, 2, 16));
        mx = fmaxf(mx, __shfl_xor(mx, 4, 16));
        mx = fmaxf(mx, __shfl_xor(mx, 8, 16));
        mloc[rr] = mx;
    }
    if (c == 0)
        for (int rr = 0; rr < 4; ++rr)
            pmaxs[mtq * 32 + nh * 16 + g * 4 + rr] = mloc[rr];
    __syncthreads();

    unsigned short* Pbuf = xbuf;   // 64 x 72 bf16, overlays dead xbuf
    for (int rr = 0; rr < 4; ++rr) {
        int lr = g * 4 + rr, row = mtq * 16 + lr;
        float m = fmaxf(pmaxs[mtq * 32 + lr], pmaxs[mtq * 32 + 16 + lr]);
        float p0 = __expf(sacc[0][rr] - m);
        float p1 = __expf(sacc[1][rr] - m);
        float s = p0 + p1;
        s += __shfl_xor(s, 1, 16);
        s += __shfl_xor(s, 2, 16);
        s += __shfl_xor(s, 4, 16);
        s += __shfl_xor(s, 8, 16);
        if (c == 0) psums[mtq * 32 + nh * 16 + lr] = s;
        Pbuf[row * 72 + nh * 32 + c] = f2bf(p0);
        Pbuf[row * 72 + nh * 32 + 16 + c] = f2bf(p1);
    }
    __syncthreads();

    // ======== PV: wave w owns out dims 32w..32w+31. K = 64 tokens.
    f32x4 oacc[4][2];
    for (int mt = 0; mt < 4; ++mt)
        for (int n2 = 0; n2 < 2; ++n2)
            oacc[mt][n2] = f32x4{0.f, 0.f, 0.f, 0.f};
    for (int kt = 0; kt < 2; ++kt) {
        short8 ap[4];
        for (int mt = 0; mt < 4; ++mt)
            ap[mt] = *(const short8*)(Pbuf + (mt * 16 + c) * 72 + kt * 32 + g * 8);
        for (int n2 = 0; n2 < 2; ++n2) {
            short8 bv = *(const short8*)(vt + (w * 32 + n2 * 16 + c) * 72 + kt * 32 + g * 8);
            for (int mt = 0; mt < 4; ++mt)
                oacc[mt][n2] = __builtin_amdgcn_mfma_f32_16x16x32_bf16(ap[mt], bv, oacc[mt][n2], 0, 0, 0);
        }
    }
    // normalize by softmax denom, write ao (overlays qbuf — q is dead)
    unsigned short* aobuf = qbuf;
    for (int mt = 0; mt < 4; ++mt)
        for (int rr = 0; rr < 4; ++rr) {
            int lr = g * 4 + rr, row = mt * 16 + lr;
            float l = psums[mt * 32 + lr] + psums[mt * 32 + 16 + lr];
            float inv = 1.0f / l;
            for (int n2 = 0; n2 < 2; ++n2)
                aobuf[row * 264 + w * 32 + n2 * 16 + c] = f2bf(oacc[mt][n2][rr] * inv);
        }
    __syncthreads();

    // ======== proj: out = ao @ Wproj + b. wave w owns out cols 32w..32w+31.
    f32x4 pacc[4][2];
    for (int mt = 0; mt < 4; ++mt)
        for (int n2 = 0; n2 < 2; ++n2)
            pacc[mt][n2] = f32x4{0.f, 0.f, 0.f, 0.f};
    for (int kt = 0; kt < 8; ++kt) {
        short8 aa[4];
        for (int mt = 0; mt < 4; ++mt)
            aa[mt] = *(const short8*)(aobuf + (mt * 16 + c) * 264 + kt * 32 + g * 8);
        for (int n2 = 0; n2 < 2; ++n2) {
            int pn = w * 2 + n2;
            short8 bp = *(const short8*)(wp_pack + ((size_t)(pn * 8 + kt) * 64 + lane) * 8);
            for (int mt = 0; mt < 4; ++mt)
                pacc[mt][n2] = __builtin_amdgcn_mfma_f32_16x16x32_bf16(aa[mt], bp, pacc[mt][n2], 0, 0, 0);
        }
    }
    for (int n2 = 0; n2 < 2; ++n2) {
        int col = w * 32 + n2 * 16 + c;
        float pb = sane(proj_b[col]);
        for (int mt = 0; mt < 4; ++mt)
            for (int rr = 0; rr < 4; ++rr) {
                int row = mt * 16 + g * 4 + rr;
                out[((size_t)b * 64 + row) * 256 + col] = pacc[mt][n2][rr] + pb;
            }
    }
}

// -------------------------------------------------------------- launch ----
extern "C" void kernel_launch(void* const* d_in, const int* in_sizes, int n_in,
                              void* d_out, int out_size, void* d_ws, size_t ws_size,
                              hipStream_t stream) {
    const float* x      = (const float*)d_in[0];
    const float* theta  = (const float*)d_in[1];
    const float* qkv_w  = (const float*)d_in[2];
    const float* qkv_b  = (const float*)d_in[3];
    const float* proj_w = (const float*)d_in[4];
    const float* proj_b = (const float*)d_in[5];
    const float* a_p    = (const float*)d_in[6];
    const float* b_p    = (const float*)d_in[7];
    const float* a_r    = (const float*)d_in[8];
    const float* b_r    = (const float*)d_in[9];
    float* out = (float*)d_out;

    // workspace: wq_pack (393216 B) | wp_pack (131072 B) | btab (1 MB)
    unsigned short* wq_pack = (unsigned short*)d_ws;
    unsigned short* wp_pack = wq_pack + 196608;
    float* btab = (float*)((char*)d_ws + 524288);

    prep_repack<<<128, 256, 0, stream>>>(qkv_w, proj_w, wq_pack, wp_pack);
    prep_bias<<<1024, 256, 0, stream>>>(theta, a_p, b_p, a_r, b_r, btab);

    hipFuncSetAttribute(reinterpret_cast<const void*>(wattn_main),
                        hipFuncAttributeMaxDynamicSharedMemorySize, LDS_BYTES);
    wattn_main<<<4096, 512, LDS_BYTES, stream>>>(x, qkv_b, proj_b, wq_pack, wp_pack, btab, out);
}